// Round 8
// baseline (214.481 us; speedup 1.0000x reference)
//
#include <hip/hip_runtime.h>

// YOLO loss: preds (B,7,7,30) f32, labels (B,7,7,30) f32 -> scalar f32 (sum/B).
// R8: algebraic split. b1 contains 0.5*p9^2, b2 contains 0.5*p4^2, noobj =
// 0.5(p4^2+p9^2)  =>  total = sum_all 0.5(p4^2+p9^2)  (K0: pure coalesced
// high-occupancy stream over preds — doubles as the env-BW probe)
//                  + sum_obj [chosen_rest - 0.5 p{4|9}^2 + cls]  (K1)
// K2 reduces both partial arrays.

#define BATCH 16384
#define S 7
#define C 30
#define NCELLS (BATCH * S * S)   // 802816
#define BLOCK 256
#define NBLK1 (NCELLS / BLOCK)    // 3136 (K1 grid)
#define NF4P  (NCELLS * C / 4)    // 6021120 float4 in preds
#define K0_BLOCKS 1470
#define K0_ITERS 16               // 1470*256*16 == 6021120 exactly

__device__ __forceinline__ float sq(float v) { return v * v; }

__device__ __forceinline__ float iou_box(float acx, float acy, float aw, float ah,
                                         float bcx, float bcy, float bw, float bh) {
    float ax0 = acx - aw * 0.5f, ax1 = acx + aw * 0.5f;
    float ay0 = acy - ah * 0.5f, ay1 = acy + ah * 0.5f;
    float bx0 = bcx - bw * 0.5f, bx1 = bcx + bw * 0.5f;
    float by0 = bcy - bh * 0.5f, by1 = bcy + bh * 0.5f;
    float iw = fmaxf(fminf(ax1, bx1) - fmaxf(ax0, bx0), 0.0f);
    float ih = fmaxf(fminf(ay1, by1) - fmaxf(ay0, by0), 0.0f);
    float inter = iw * ih;
    float denom = aw * ah + bw * bh - inter + 1e-10f;
    return inter / denom;
}

// ---- K0: coalesced stream over preds; acc += 0.5*x^2 where flat%30 in {4,9}
// component mask per (float4 idx % 15): nonzero only m=1(bit0),2(bit1),8(bit2),9(bit3)
__global__ __launch_bounds__(BLOCK) void yolo_presum_kernel(
        const float4* __restrict__ preds4,
        float* __restrict__ partials) {
    const int tid = blockIdx.x * BLOCK + threadIdx.x;
    const int stride = K0_BLOCKS * BLOCK;   // 376320
    float a0 = 0.f, a1 = 0.f, a2 = 0.f, a3 = 0.f;
    #pragma unroll
    for (int k = 0; k < K0_ITERS; k += 4) {
        int i0 = tid + (k + 0) * stride;
        int i1 = tid + (k + 1) * stride;
        int i2 = tid + (k + 2) * stride;
        int i3 = tid + (k + 3) * stride;
        float4 v0 = preds4[i0];
        float4 v1 = preds4[i1];
        float4 v2 = preds4[i2];
        float4 v3 = preds4[i3];
        unsigned s0 = (unsigned)((0x8400000210ull >> (4 * (i0 % 15))) & 15ull);
        unsigned s1 = (unsigned)((0x8400000210ull >> (4 * (i1 % 15))) & 15ull);
        unsigned s2 = (unsigned)((0x8400000210ull >> (4 * (i2 % 15))) & 15ull);
        unsigned s3 = (unsigned)((0x8400000210ull >> (4 * (i3 % 15))) & 15ull);
        a0 += ((s0 & 1u) ? 0.5f * v0.x * v0.x : 0.f) + ((s0 & 2u) ? 0.5f * v0.y * v0.y : 0.f)
            + ((s0 & 4u) ? 0.5f * v0.z * v0.z : 0.f) + ((s0 & 8u) ? 0.5f * v0.w * v0.w : 0.f);
        a1 += ((s1 & 1u) ? 0.5f * v1.x * v1.x : 0.f) + ((s1 & 2u) ? 0.5f * v1.y * v1.y : 0.f)
            + ((s1 & 4u) ? 0.5f * v1.z * v1.z : 0.f) + ((s1 & 8u) ? 0.5f * v1.w * v1.w : 0.f);
        a2 += ((s2 & 1u) ? 0.5f * v2.x * v2.x : 0.f) + ((s2 & 2u) ? 0.5f * v2.y * v2.y : 0.f)
            + ((s2 & 4u) ? 0.5f * v2.z * v2.z : 0.f) + ((s2 & 8u) ? 0.5f * v2.w * v2.w : 0.f);
        a3 += ((s3 & 1u) ? 0.5f * v3.x * v3.x : 0.f) + ((s3 & 2u) ? 0.5f * v3.y * v3.y : 0.f)
            + ((s3 & 4u) ? 0.5f * v3.z * v3.z : 0.f) + ((s3 & 8u) ? 0.5f * v3.w * v3.w : 0.f);
    }
    float acc = (a0 + a1) + (a2 + a3);

    #pragma unroll
    for (int off = 32; off > 0; off >>= 1)
        acc += __shfl_down(acc, off, 64);
    __shared__ float wsum[BLOCK / 64];
    int lane = threadIdx.x & 63, wv = threadIdx.x >> 6;
    if (lane == 0) wsum[wv] = acc;
    __syncthreads();
    if (threadIdx.x == 0)
        partials[blockIdx.x] = wsum[0] + wsum[1] + wsum[2] + wsum[3];
}

// ---- K1: obj-only remainder. Cheap path = one l4 load, contributes 0.
__global__ __launch_bounds__(BLOCK) void yolo_obj_kernel(
        const float* __restrict__ preds,
        const float* __restrict__ labels,
        float* __restrict__ partials) {
    const int tid  = threadIdx.x;
    const int cell = blockIdx.x * BLOCK + tid;

    const float* p = preds  + (size_t)cell * C;
    const float* l = labels + (size_t)cell * C;

    float l4 = l[4];
    float loss = 0.0f;
    if (l4 == 1.0f) {
        float2 p01 = *reinterpret_cast<const float2*>(p + 0);
        float2 p23 = *reinterpret_cast<const float2*>(p + 2);
        float2 p45 = *reinterpret_cast<const float2*>(p + 4);
        float2 p67 = *reinterpret_cast<const float2*>(p + 6);
        float2 p89 = *reinterpret_cast<const float2*>(p + 8);
        float2 l01 = *reinterpret_cast<const float2*>(l + 0);
        float2 l23 = *reinterpret_cast<const float2*>(l + 2);
        float2 l45 = *reinterpret_cast<const float2*>(l + 4);
        float2 l67 = *reinterpret_cast<const float2*>(l + 6);
        float2 l89 = *reinterpret_cast<const float2*>(l + 8);

        // transposed label x-coord quirk: labels[b, x, y, 0]
        int b   = cell / (S * S);
        int rem = cell - b * (S * S);
        int y   = rem / S;
        int x   = rem - y * S;
        int pc  = b * (S * S) + x * S + y;
        float lb0 = labels[(size_t)pc * C];

        float iou1 = iou_box(p01.x, p01.y, p23.x, p23.y, lb0, l01.y, l23.x, l23.y);
        float iou2 = iou_box(p45.y, p67.x, p67.y, p89.x, lb0, l01.y, l23.x, l23.y);

        // rest1 = b1 + cls - 0.5 p4^2 - 0.5 p9^2  (b1 carried 0.5 p9^2)
        float rest1 = 5.0f * (sq(p01.x - l01.x) + sq(p01.y - l01.y))
                    + sq(sqrtf(p23.x) - sqrtf(l23.x)) + sq(sqrtf(p23.y) - sqrtf(l23.y))
                    + sq(iou1 - p45.x)
                    - 0.5f * p45.x * p45.x;
        float rest2 = 5.0f * (sq(p45.y - l45.y) + sq(p67.x - l67.x))
                    + sq(sqrtf(p67.y) - sqrtf(l67.y)) + sq(sqrtf(p89.x) - sqrtf(l89.x))
                    + sq(iou2 - p89.y)
                    - 0.5f * p89.y * p89.y;

        float cls = 0.0f;
        #pragma unroll
        for (int i = 0; i < 10; ++i) {
            float2 pc2 = *reinterpret_cast<const float2*>(p + 10 + 2 * i);
            float2 lc2 = *reinterpret_cast<const float2*>(l + 10 + 2 * i);
            cls += sq(lc2.x - pc2.x) + sq(lc2.y - pc2.y);
        }

        loss = ((iou1 > iou2) ? rest1 : rest2) + cls;
    }

    #pragma unroll
    for (int off = 32; off > 0; off >>= 1)
        loss += __shfl_down(loss, off, 64);
    __shared__ float wsum[BLOCK / 64];
    int lane = tid & 63, wv = tid >> 6;
    if (lane == 0) wsum[wv] = loss;
    __syncthreads();
    if (tid == 0)
        partials[blockIdx.x] = wsum[0] + wsum[1] + wsum[2] + wsum[3];
}

// ---- K2: sum both partial arrays -> out
__global__ __launch_bounds__(BLOCK) void yolo_reduce_kernel(
        const float* __restrict__ ws,
        float* __restrict__ out) {
    const int tid = threadIdx.x;
    float s = 0.0f;
    for (int i = tid; i < NBLK1; i += BLOCK)     s += ws[i];
    for (int i = tid; i < K0_BLOCKS; i += BLOCK) s += ws[NBLK1 + i];

    #pragma unroll
    for (int off = 32; off > 0; off >>= 1)
        s += __shfl_down(s, off, 64);
    __shared__ float wsum[BLOCK / 64];
    int lane = tid & 63, wv = tid >> 6;
    if (lane == 0) wsum[wv] = s;
    __syncthreads();
    if (tid == 0)
        out[0] = (wsum[0] + wsum[1] + wsum[2] + wsum[3]) * (1.0f / (float)BATCH);
}

extern "C" void kernel_launch(void* const* d_in, const int* in_sizes, int n_in,
                              void* d_out, int out_size, void* d_ws, size_t ws_size,
                              hipStream_t stream) {
    const float* preds  = (const float*)d_in[0];
    const float* labels = (const float*)d_in[1];
    float* out = (float*)d_out;
    float* ws  = (float*)d_ws;   // [0:3136) K1 partials, [3136:3136+1470) K0 partials

    yolo_presum_kernel<<<K0_BLOCKS, BLOCK, 0, stream>>>(
        reinterpret_cast<const float4*>(preds), ws + NBLK1);
    yolo_obj_kernel<<<NBLK1, BLOCK, 0, stream>>>(preds, labels, ws);
    yolo_reduce_kernel<<<1, BLOCK, 0, stream>>>(ws, out);
}